// Round 3
// baseline (7970.036 us; speedup 1.0000x reference)
//
#include <hip/hip_runtime.h>
#include <stdint.h>
#include <stddef.h>

#define TT 1024
#define BB 64
#define HH 1024
#define II 1024

typedef __attribute__((ext_vector_type(8))) short s16x8;
typedef __attribute__((ext_vector_type(4))) float f32x4;

// ---- workspace layout (bytes) ----
// 512  : flags[4][64] u32   (group*256B + (slice*4+wave)*4)
// 4096 : ring: group*65536 + slot*32768 + row*2048 + feat*2
//        (4 groups, 2 slots, 16 rows, 1024 bf16 features)
#define WS_FLAGS 512
#define WS_RING  4096

static __device__ __forceinline__ unsigned short f2bf(float f) {
    union { float f; unsigned int u; } v; v.f = f;
    return (unsigned short)((v.u + 0x7fffu + ((v.u >> 16) & 1u)) >> 16);
}

static __device__ __forceinline__ s16x8 pack8(float4 a, float4 b) {
    s16x8 v;
    v[0] = (short)f2bf(a.x); v[1] = (short)f2bf(a.y);
    v[2] = (short)f2bf(a.z); v[3] = (short)f2bf(a.w);
    v[4] = (short)f2bf(b.x); v[5] = (short)f2bf(b.y);
    v[6] = (short)f2bf(b.z); v[7] = (short)f2bf(b.w);
    return v;
}

static __device__ __forceinline__ f32x4 zero4() {
    f32x4 v = {0.f, 0.f, 0.f, 0.f};
    return v;
}

// Device-coherent-point access: sc0 sc1 = bypass L1 and L2 (read-through /
// write-through). Placement-independent: correct for any XCD assignment.
static __device__ __forceinline__ s16x8 ldA(const void* p) {
    s16x8 v;
    asm volatile("global_load_dwordx4 %0, %1, off sc0 sc1" : "=v"(v) : "v"(p));
    return v;
}
static __device__ __forceinline__ void st_ring(void* p, unsigned short val) {
    unsigned v32 = val;
    asm volatile("global_store_short %0, %1, off sc0 sc1" :: "v"(p), "v"(v32) : "memory");
}
#define WAITV(n) do { asm volatile("s_waitcnt vmcnt(" #n ")" ::: "memory"); \
                      __builtin_amdgcn_sched_barrier(0); } while (0)

// ---------------------------------------------------------------------------
// Kernel 0: zero the control region of the workspace (runs every launch).
// ---------------------------------------------------------------------------
__global__ void init_ws(unsigned int* w) {
#pragma unroll
    for (int i = 0; i < 4; ++i)
        w[threadIdx.x * 4 + i] = 0u;   // 256 threads * 16 B = 4096 B
}

// ---------------------------------------------------------------------------
// Kernel 1: xw = x @ W_ih^T + b_ih + b_hh -> d_out states area (unchanged,
// worked in round 1).
// ---------------------------------------------------------------------------
__global__ __launch_bounds__(256, 2) void xw_gemm(
    const float* __restrict__ X,
    const float* __restrict__ Wih,
    const float* __restrict__ bih,
    const float* __restrict__ bhh,
    float* __restrict__ out)
{
    __shared__ unsigned short As[128 * 64];
    __shared__ unsigned short Bs[128 * 64];

    const int tid  = threadIdx.x;
    const int lane = tid & 63;
    const int wid  = tid >> 6;
    const int bm = blockIdx.x >> 3;
    const int bn = blockIdx.x & 7;
    const size_t m0 = (size_t)bm * 128;
    const int n0 = bn * 128;
    const int wm = (wid >> 1) * 64;
    const int wn = (wid & 1) * 64;

    f32x4 acc[4][4];
#pragma unroll
    for (int i = 0; i < 4; ++i)
#pragma unroll
        for (int j = 0; j < 4; ++j) acc[i][j] = zero4();

    const int srow  = tid >> 1;
    const int shalf = tid & 1;
    const float* xp = X   + (m0 + srow) * (size_t)II + shalf * 32;
    const float* wp = Wih + (size_t)(n0 + srow) * II + shalf * 32;

    for (int kt = 0; kt < II / 64; ++kt) {
#pragma unroll
        for (int i = 0; i < 4; ++i) {
            float4 a0 = *(const float4*)(xp + i * 8);
            float4 a1 = *(const float4*)(xp + i * 8 + 4);
            float4 b0 = *(const float4*)(wp + i * 8);
            float4 b1 = *(const float4*)(wp + i * 8 + 4);
            const int c = shalf * 4 + i;
            const int cw = (c ^ (srow & 7)) << 3;
            *(s16x8*)&As[srow * 64 + cw] = pack8(a0, a1);
            *(s16x8*)&Bs[srow * 64 + cw] = pack8(b0, b1);
        }
        __syncthreads();

#pragma unroll
        for (int kk = 0; kk < 2; ++kk) {
            s16x8 af[4], bf[4];
            const int cs = kk * 4 + (lane >> 4);
#pragma unroll
            for (int mi = 0; mi < 4; ++mi) {
                const int r = wm + mi * 16 + (lane & 15);
                af[mi] = *(const s16x8*)&As[r * 64 + ((cs ^ (r & 7)) << 3)];
            }
#pragma unroll
            for (int ni = 0; ni < 4; ++ni) {
                const int r = wn + ni * 16 + (lane & 15);
                bf[ni] = *(const s16x8*)&Bs[r * 64 + ((cs ^ (r & 7)) << 3)];
            }
#pragma unroll
            for (int mi = 0; mi < 4; ++mi)
#pragma unroll
                for (int ni = 0; ni < 4; ++ni)
                    acc[mi][ni] = __builtin_amdgcn_mfma_f32_16x16x32_bf16(
                        af[mi], bf[ni], acc[mi][ni], 0, 0, 0);
        }
        __syncthreads();
        xp += 64; wp += 64;
    }

#pragma unroll
    for (int ni = 0; ni < 4; ++ni) {
        const int col = n0 + wn + ni * 16 + (lane & 15);
        const float bias = bih[col] + bhh[col];
#pragma unroll
        for (int mi = 0; mi < 4; ++mi) {
            const size_t row = m0 + wm + mi * 16 + ((lane >> 4) << 2);
#pragma unroll
            for (int r = 0; r < 4; ++r)
                out[(row + r) * (size_t)HH + col] = acc[mi][ni][r] + bias;
        }
    }
}

// ---------------------------------------------------------------------------
// Kernel 2: persistent scan. 64 blocks x 256 thr (trivially all resident).
// 4 groups x 16 slices; group g owns batch rows [16g,16g+16). Wave = 16
// features, W slice in 128 VGPRs. Per step: poll 64 per-wave flags (agent
// relaxed atomics) -> 32 pipelined sc0sc1 A-loads from ring -> 32 MFMA ->
// tanh -> states + hr_{t+1} (sc0sc1) -> vmcnt(0) -> publish flag (relaxed).
// No LDS, no __syncthreads, no XCD/placement assumptions.
// ---------------------------------------------------------------------------
__global__ __launch_bounds__(256, 1) void rnn_scan(
    const float* __restrict__ Whh,
    float* __restrict__ out,
    void* __restrict__ ws)
{
    const int tid  = threadIdx.x;
    const int lane = tid & 63;
    const int wid  = tid >> 6;
    const int g  = blockIdx.x >> 4;     // 0..3 batch group
    const int sl = blockIdx.x & 15;     // 0..15 feature slice

    const int j  = sl * 64 + wid * 16 + (lane & 15);  // output feature (B col)
    const int kg = lane >> 4;                          // 0..3 k-quadrant / row-quadrant

    // ---- one-time: this wave's 16 W_hh rows -> 128 VGPRs of B-fragments ----
    s16x8 bfr[32];
    {
        const float* wr = Whh + (size_t)j * HH + kg * 8;
#pragma unroll
        for (int c = 0; c < 32; ++c) {
            float4 p0 = *(const float4*)(wr + c * 32);
            float4 p1 = *(const float4*)(wr + c * 32 + 4);
            bfr[c] = pack8(p0, p1);
        }
    }

    const int arow = lane & 15;   // A batch row within group (all 16 valid)
    unsigned* fl = (unsigned*)((char*)ws + WS_FLAGS) + g * 64;
    unsigned* myflag = fl + sl * 4 + wid;
    char* rg = (char*)ws + WS_RING + (size_t)g * 65536;
    const char* pa0 = rg + arow * 2048 + kg * 16;           // slot 0 A base
    const char* pa1 = pa0 + 32768;                           // slot 1 A base

    float hprev[4];

    // ---- t = 0: h = tanh(xw); hr_1 = 0.5*h -> slot 1 ----
#pragma unroll
    for (int r = 0; r < 4; ++r) {
        const int b = g * 16 + kg * 4 + r;
        const size_t idx = ((size_t)b * TT) * HH + j;
        const float h = tanhf(out[idx]);
        out[idx] = h;
        hprev[r] = h;
        st_ring(rg + 32768 + (kg * 4 + r) * 2048 + j * 2, f2bf(0.5f * h));
    }
    asm volatile("s_waitcnt vmcnt(0)" ::: "memory");
    if (lane == 0)
        __hip_atomic_store(myflag, 1u, __ATOMIC_RELAXED, __HIP_MEMORY_SCOPE_AGENT);

#pragma unroll 1
    for (int t = 1; t < TT; ++t) {
        // ---- xw prefetch (HBM latency hides under the poll) ----
        float xwv[4]; size_t xidx[4];
#pragma unroll
        for (int r = 0; r < 4; ++r) {
            const int b = g * 16 + kg * 4 + r;
            xidx[r] = ((size_t)b * TT + t) * HH + j;
            xwv[r] = out[xidx[r]];
        }

        // ---- poll all 64 producer flags >= t (agent relaxed atomics) ----
        {
            const unsigned* myp = fl + lane;
            for (;;) {
                unsigned v = __hip_atomic_load(myp, __ATOMIC_RELAXED,
                                               __HIP_MEMORY_SCOPE_AGENT);
                if (__all((int)(v >= (unsigned)t))) break;
                __builtin_amdgcn_s_sleep(1);
            }
            asm volatile("" ::: "memory");
            __builtin_amdgcn_sched_barrier(0);
        }

        // ---- 32 pipelined A-loads (device-point) + 32 MFMA ----
        const char* p = (t & 1) ? pa1 : pa0;
        s16x8 ab[32];
        f32x4 acc[4];
#pragma unroll
        for (int i = 0; i < 4; ++i) acc[i] = zero4();

#pragma unroll
        for (int c = 0; c < 16; ++c) { ab[c] = ldA(p); p += 64; }
#pragma unroll
        for (int cg = 0; cg < 8; ++cg) {
            if (cg < 4) {
#pragma unroll
                for (int c2 = 0; c2 < 4; ++c2) {
                    ab[16 + cg * 4 + c2] = ldA(p); p += 64;
                }
            }
            if (cg < 4)      { WAITV(16); }
            else if (cg == 4){ WAITV(12); }
            else if (cg == 5){ WAITV(8);  }
            else if (cg == 6){ WAITV(4);  }
            else             { WAITV(0);  }
#pragma unroll
            for (int c2 = 0; c2 < 4; ++c2) {
                const int c = cg * 4 + c2;
                acc[c2] = __builtin_amdgcn_mfma_f32_16x16x32_bf16(
                    ab[c], bfr[c], acc[c2], 0, 0, 0);
            }
        }

        f32x4 accT = acc[0] + acc[1] + acc[2] + acc[3];

        // ---- epilogue: tanh, states, hr_{t+1}, publish ----
        char* rw = rg + (size_t)((t + 1) & 1) * 32768;
#pragma unroll
        for (int r = 0; r < 4; ++r) {
            const float h = tanhf(accT[r] + xwv[r]);
            out[xidx[r]] = h;
            if (t == TT - 1)
                out[(size_t)BB * TT * HH +
                    (size_t)(g * 16 + kg * 4 + r) * HH + j] = h;
            st_ring(rw + (kg * 4 + r) * 2048 + j * 2, f2bf(0.5f * (h + hprev[r])));
            hprev[r] = h;
        }
        if (t < TT - 1) {
            asm volatile("s_waitcnt vmcnt(0)" ::: "memory");
            if (lane == 0)
                __hip_atomic_store(myflag, (unsigned)(t + 1),
                                   __ATOMIC_RELAXED, __HIP_MEMORY_SCOPE_AGENT);
        }
    }
}

// ---------------------------------------------------------------------------
extern "C" void kernel_launch(void* const* d_in, const int* in_sizes, int n_in,
                              void* d_out, int out_size, void* d_ws, size_t ws_size,
                              hipStream_t stream)
{
    const float* X   = (const float*)d_in[0];
    const float* Wih = (const float*)d_in[1];
    const float* Whh = (const float*)d_in[2];
    const float* bih = (const float*)d_in[3];
    const float* bhh = (const float*)d_in[4];
    float* out = (float*)d_out;

    init_ws<<<dim3(1), dim3(256), 0, stream>>>((unsigned int*)d_ws);
    xw_gemm<<<dim3(4096), dim3(256), 0, stream>>>(X, Wih, bih, bhh, out);
    rnn_scan<<<dim3(64), dim3(256), 0, stream>>>(Whh, out, d_ws);
}